// Round 2
// 191.046 us; speedup vs baseline: 1.0058x; 1.0058x over previous
//
#include <hip/hip_runtime.h>
#include <hip/hip_fp16.h>

// MLPLowRankPredictor: FastFood (B,H,P,G,H,S) low-rank weight perturbation + 3-layer MLP.
// SEQ=64 BATCH=32 -> N=2048 tokens. Z=128, X=32, H=128, Y=16.
// Blocks: wd0: 0..31 (4 rows x 32 cols each), bd0: 32, wd1: 33..160 (1 row each),
//         bd1: 161, wd2: 162..177 (1 row each), bd2: 178 (first 16 elems).
//
// R1 changes vs baseline (192 us):
//  - LDS permute buffer 32KB -> 16KB via packed fp16 (half2 per dword, [k/2][lane]).
//    LDS was the occupancy cap (5 blocks/CU = 15.6%); now VGPR-capped (8/CU = 25%).
//  - Dedup bias ff-blocks: computed ONCE per token (K1 b=32/33/34) instead of being
//    recomputed per weight-block in K1 (x32) and K3 (x16). K2 fuses relu(h1_part+bd0).
// (R1 resubmitted unchanged: previous round was an MI355X container infra failure.)

#define ZD 128
#define XD 32
#define HD 128
#define YD 16
#define NTOK 2048

__device__ __forceinline__ void fwht128(float v[128]) {
#pragma unroll
  for (int s = 1; s < 128; s <<= 1) {
#pragma unroll
    for (int p = 0; p < 128; p++) {
      if ((p & s) == 0) {
        float a = v[p], b = v[p + s];
        v[p] = a + b;
        v[p + s] = a - b;
      }
    }
  }
}

__device__ __forceinline__ void load128(float v[128], const float* __restrict__ src) {
  const float4* s4 = (const float4*)src;
#pragma unroll
  for (int k = 0; k < 32; k++) {
    float4 f = s4[k];
    v[4 * k + 0] = f.x; v[4 * k + 1] = f.y; v[4 * k + 2] = f.z; v[4 * k + 3] = f.w;
  }
}

// v holds z on entry; on exit v = ffS * FWHT( ffG * perm( FWHT( ffB * z ) ) )
// (the final /128 is applied by the consumer).
// LDS: 64x64 dwords (16 KB). Dword d = (k>>1)*64+lane holds half2(v[2m],v[2m+1]).
// Bank: d%32 = lane%32 -> 2 lanes/bank (free). Intermediate |v| <= ~60, fp16-safe;
// rel err 2^-11 quantization is crushed by S(0.01)/128 scaling -> ~2e-5 on output.
__device__ __forceinline__ void ff_block(float v[128], unsigned int* lds, int lane,
    const float* __restrict__ ffB, const float* __restrict__ ffG,
    const float* __restrict__ ffS, const int* __restrict__ ffP, int j) {
  const float* Bj = ffB + j * ZD;
  const float* Gj = ffG + j * ZD;
  const float* Sj = ffS + j * ZD;
  const int*   Pj = ffP + j * ZD;
#pragma unroll
  for (int k = 0; k < 128; k++) v[k] *= Bj[k];   // uniform -> s_load
  fwht128(v);
  __syncthreads();                                // WAR vs any previous lds reads
#pragma unroll
  for (int m = 0; m < 64; m++) {
    __half2 h2 = __floats2half2_rn(v[2 * m], v[2 * m + 1]);
    lds[m * 64 + lane] = *(const unsigned int*)&h2;
  }
  __syncthreads();
  const __half* ldsh = (const __half*)lds;
#pragma unroll
  for (int k = 0; k < 128; k++) {
    int pk = Pj[k];                               // uniform -> s_load
    v[k] = Gj[k] * __half2float(ldsh[(pk >> 1) * 128 + 2 * lane + (pk & 1)]);
  }
  fwht128(v);
#pragma unroll
  for (int k = 0; k < 128; k++) v[k] *= Sj[k];
}

// K1: grid (32, 35). b<32: weight rows 4b..4b+3 -> h1_part (no bd0, no relu).
//     b=32: bd0 block -> bd0v.  b=33: bd1 block -> h2_bias.  b=34: bd2 block -> bd2v.
__global__ __launch_bounds__(64) void k1_layer0(
    const float* __restrict__ x, const float* __restrict__ z,
    const float* __restrict__ W0, const float* __restrict__ b0,
    const float* __restrict__ ffB, const float* __restrict__ ffG,
    const float* __restrict__ ffS, const int* __restrict__ ffP,
    float* __restrict__ h1_part, float* __restrict__ bd0v,
    float* __restrict__ h2_bias, float* __restrict__ bd2v) {
  __shared__ unsigned int lds[64 * 64];
  const int lane = threadIdx.x;
  const int tg = blockIdx.x;   // token group 0..31
  const int b  = blockIdx.y;   // 0..34
  const int t = tg * 64 + lane;

  float v[128];
  load128(v, z + (size_t)t * ZD);

  if (b < 32) {
    float xi[32];
    {
      const float4* x4 = (const float4*)(x + (size_t)t * XD);
#pragma unroll
      for (int k = 0; k < 8; k++) {
        float4 f = x4[k];
        xi[4 * k] = f.x; xi[4 * k + 1] = f.y; xi[4 * k + 2] = f.z; xi[4 * k + 3] = f.w;
      }
    }
    ff_block(v, lds, lane, ffB, ffG, ffS, ffP, b);
    float4 o;
    float* op = &o.x;
#pragma unroll
    for (int r = 0; r < 4; r++) {
      float aw = 0.f, ab = 0.f;
#pragma unroll
      for (int i = 0; i < 32; i++) {
        aw += v[r * 32 + i] * xi[i];
        ab += W0[(4 * b + r) * 32 + i] * xi[i];   // uniform -> s_load
      }
      op[r] = ab + b0[4 * b + r] + aw * (1.0f / 128.0f);  // pre-relu, pre-bd0
    }
    *(float4*)(h1_part + (size_t)t * HD + 4 * b) = o;
  } else if (b == 32) {
    ff_block(v, lds, lane, ffB, ffG, ffS, ffP, 32);
    float4* o4 = (float4*)(bd0v + (size_t)t * HD);
#pragma unroll
    for (int k = 0; k < 32; k++)
      o4[k] = make_float4(v[4 * k] * (1.0f / 128.0f), v[4 * k + 1] * (1.0f / 128.0f),
                          v[4 * k + 2] * (1.0f / 128.0f), v[4 * k + 3] * (1.0f / 128.0f));
  } else if (b == 33) {
    ff_block(v, lds, lane, ffB, ffG, ffS, ffP, 161);
    float4* o4 = (float4*)(h2_bias + (size_t)t * HD);
#pragma unroll
    for (int k = 0; k < 32; k++)
      o4[k] = make_float4(v[4 * k] * (1.0f / 128.0f), v[4 * k + 1] * (1.0f / 128.0f),
                          v[4 * k + 2] * (1.0f / 128.0f), v[4 * k + 3] * (1.0f / 128.0f));
  } else {
    ff_block(v, lds, lane, ffB, ffG, ffS, ffP, 178);
#pragma unroll
    for (int k = 0; k < 16; k++)
      bd2v[k * NTOK + t] = v[k] * (1.0f / 128.0f);   // [b][t], coalesced both sides
  }
}

// K2: grid (32, 128). One wd1 row per block; h1 = relu(h1_part + bd0v) fused inline.
__global__ __launch_bounds__(64) void k2_layer1(
    const float* __restrict__ z,
    const float* __restrict__ W1, const float* __restrict__ b1,
    const float* __restrict__ ffB, const float* __restrict__ ffG,
    const float* __restrict__ ffS, const int* __restrict__ ffP,
    const float* __restrict__ h1_part, const float* __restrict__ bd0v,
    float* __restrict__ h2_part) {
  __shared__ unsigned int lds[64 * 64];
  const int lane = threadIdx.x;
  const int tg = blockIdx.x;   // 0..31
  const int jr = blockIdx.y;   // 0..127 weight row
  const int t = tg * 64 + lane;

  float v[128];
  load128(v, z + (size_t)t * ZD);
  ff_block(v, lds, lane, ffB, ffG, ffS, ffP, 33 + jr);

  const float4* h4 = (const float4*)(h1_part + (size_t)t * HD);
  const float4* d4 = (const float4*)(bd0v + (size_t)t * HD);
  const float* W1r = W1 + (size_t)jr * 128;
  float aw0 = 0.f, aw1 = 0.f, ab0 = 0.f, ab1 = 0.f;
#pragma unroll
  for (int k = 0; k < 32; k++) {
    float4 a = h4[k], d = d4[k];
    float e0 = fmaxf(a.x + d.x, 0.f), e1 = fmaxf(a.y + d.y, 0.f);
    float e2 = fmaxf(a.z + d.z, 0.f), e3 = fmaxf(a.w + d.w, 0.f);
    aw0 += v[4 * k + 0] * e0 + v[4 * k + 2] * e2;
    aw1 += v[4 * k + 1] * e1 + v[4 * k + 3] * e3;
    ab0 += W1r[4 * k + 0] * e0 + W1r[4 * k + 2] * e2;   // uniform -> s_load
    ab1 += W1r[4 * k + 1] * e1 + W1r[4 * k + 3] * e3;
  }
  float val = (ab0 + ab1) + b1[jr] + (aw0 + aw1) * (1.0f / 128.0f);
  h2_part[(size_t)t * HD + jr] = val;   // pre-relu partial (bd1 added in K3)
}

// K3: grid (32, 16). One wd2 row per block; bd2 read from bd2v (computed once in K1).
__global__ __launch_bounds__(64) void k3_layer2(
    const float* __restrict__ z,
    const float* __restrict__ W2, const float* __restrict__ b2,
    const float* __restrict__ ffB, const float* __restrict__ ffG,
    const float* __restrict__ ffS, const int* __restrict__ ffP,
    const float* __restrict__ h2_part, const float* __restrict__ h2_bias,
    const float* __restrict__ bd2v, float* __restrict__ out) {
  __shared__ unsigned int lds[64 * 64];
  const int lane = threadIdx.x;
  const int tg = blockIdx.x;   // 0..31
  const int b  = blockIdx.y;   // 0..15 output row
  const int t = tg * 64 + lane;

  float v[128];
  load128(v, z + (size_t)t * ZD);
  ff_block(v, lds, lane, ffB, ffG, ffS, ffP, 162 + b);

  const float4* p4 = (const float4*)(h2_part + (size_t)t * HD);
  const float4* q4 = (const float4*)(h2_bias + (size_t)t * HD);
  const float* W2r = W2 + (size_t)b * 128;
  float aw = 0.f, ab = 0.f;
#pragma unroll
  for (int k = 0; k < 32; k++) {
    float4 p = p4[k], q = q4[k];
    float e0 = fmaxf(p.x + q.x, 0.f), e1 = fmaxf(p.y + q.y, 0.f);
    float e2 = fmaxf(p.z + q.z, 0.f), e3 = fmaxf(p.w + q.w, 0.f);
    aw += v[4 * k] * e0 + v[4 * k + 1] * e1 + v[4 * k + 2] * e2 + v[4 * k + 3] * e3;
    ab += W2r[4 * k] * e0 + W2r[4 * k + 1] * e1 + W2r[4 * k + 2] * e2 + W2r[4 * k + 3] * e3;
  }

  float bd2 = bd2v[b * NTOK + t];
  out[(size_t)t * YD + b] = ab + b2[b] + aw * (1.0f / 128.0f) + bd2;
}

extern "C" void kernel_launch(void* const* d_in, const int* in_sizes, int n_in,
                              void* d_out, int out_size, void* d_ws, size_t ws_size,
                              hipStream_t stream) {
  const float* x  = (const float*)d_in[0];
  const float* z  = (const float*)d_in[1];
  const float* W0 = (const float*)d_in[2];
  const float* b0 = (const float*)d_in[3];
  const float* W1 = (const float*)d_in[4];
  const float* b1 = (const float*)d_in[5];
  const float* W2 = (const float*)d_in[6];
  const float* b2 = (const float*)d_in[7];
  const float* fB = (const float*)d_in[8];
  const float* fG = (const float*)d_in[9];
  const float* fS = (const float*)d_in[10];
  const int*   fP = (const int*)d_in[11];
  float* out = (float*)d_out;

  float* h1_part = (float*)d_ws;             // 2048*128 f32 = 1 MB (pre-relu, no bd0)
  float* h2_part = h1_part + NTOK * HD;      // 1 MB (pre-relu, W1*h + b1 + wd part)
  float* h2_bias = h2_part + NTOK * HD;      // 1 MB (bd1 part, /128 applied)
  float* bd0v    = h2_bias + NTOK * HD;      // 1 MB (bd0 part, /128 applied)
  float* bd2v    = bd0v + NTOK * HD;         // 128 KB (bd2 part, [b][t], /128 applied)

  k1_layer0<<<dim3(32, 35), 64, 0, stream>>>(x, z, W0, b0, fB, fG, fS, fP,
                                             h1_part, bd0v, h2_bias, bd2v);
  k2_layer1<<<dim3(32, 128), 64, 0, stream>>>(z, W1, b1, fB, fG, fS, fP,
                                              h1_part, bd0v, h2_part);
  k3_layer2<<<dim3(32, 16), 64, 0, stream>>>(z, W2, b2, fB, fG, fS, fP,
                                             h2_part, h2_bias, bd2v, out);
}